// Round 9
// baseline (237.873 us; speedup 1.0000x reference)
//
#include <hip/hip_runtime.h>

#define BT 32
#define CH 64
#define HS 56
#define WS 56
#define HH 28
#define WH 28

// ---------------- filter constants (exact reference values) ----------------
namespace {
constexpr float ISQ2 = 0.70710678118654752440f;
constexpr float F_H0[13] = {-0.0017578125f, 0.0f, 0.022265625f, -0.046875f,
    -0.0482421875f, 0.296875f, 0.55546875f, 0.296875f, -0.0482421875f,
    -0.046875f, 0.022265625f, 0.0f, -0.0017578125f};
constexpr float F_H1[19] = {-7.0626e-05f, 0.0f, 0.00134189f, -0.00188341f,
    -0.0071566f, 0.023856f, 0.0556431f, -0.0516881f, -0.299758f, 0.559431f,
    -0.299758f, -0.0516881f, 0.0556431f, 0.023856f, -0.0071566f,
    -0.00188341f, 0.00134189f, 0.0f, -7.0626e-05f};
constexpr float F_G0[19] = {7.0626e-05f, 0.0f, -0.00134189f, -0.00188341f,
    0.0071566f, 0.023856f, -0.0556431f, -0.0516881f, 0.299758f, 0.559431f,
    0.299758f, -0.0516881f, -0.0556431f, 0.023856f, 0.0071566f,
    -0.00188341f, -0.00134189f, 0.0f, 7.0626e-05f};
constexpr float F_G1[13] = {-0.0017578125f, 0.0f, 0.022265625f, 0.046875f,
    -0.0482421875f, -0.296875f, 0.55546875f, -0.296875f, -0.0482421875f,
    0.046875f, 0.022265625f, 0.0f, -0.0017578125f};
}

__device__ __forceinline__ int symi(int k) {
    k = (k < 0) ? (-1 - k) : k;
    k = (k >= HS) ? (2 * HS - 1 - k) : k;
    return k;
}

__device__ __forceinline__ unsigned short f2bf(float f) {  // RNE bf16
    unsigned u = __float_as_uint(f);
    u += 0x7fffu + ((u >> 16) & 1u);
    return (unsigned short)(u >> 16);
}
__device__ __forceinline__ float bf2f(unsigned short h) {
    return __uint_as_float(((unsigned)h) << 16);
}

typedef __attribute__((ext_vector_type(8))) short short8;  // 8 bf16 (4 VGPR)
typedef __attribute__((ext_vector_type(4))) float f32x4;

// sbT layout: plane p = s*2 + ri (12 planes), [p][c 64][b 32][pos 784], bf16
#define PPOS 784
#define PS (BT * PPOS)  // stride per c-step = 25088

// ---- K0: transpose w_ll [c][h][w] -> wllT [h][w][c] (staged in d_out head)
__global__ __launch_bounds__(256) void k_wll_T(const float* __restrict__ wll,
                                               float* __restrict__ wllT) {
    __shared__ float tile[64][65];
    int pos0 = blockIdx.x * 64;
    int lp = threadIdx.x & 63, g = threadIdx.x >> 6;
#pragma unroll
    for (int r = 0; r < 16; ++r) {
        int cc = r * 4 + g;
        tile[cc][lp] = wll[cc * (HS * WS) + pos0 + lp];
    }
    __syncthreads();
#pragma unroll
    for (int r = 0; r < 16; ++r) {
        int pl = r * 4 + g;
        wllT[(pos0 + pl) * CH + lp] = tile[lp][pl];
    }
}

// ---- K1: forward row filters (sliding window, no LDS): x -> lo, hi (bf16)
__global__ __launch_bounds__(256) void k_fwd_rows(const float* __restrict__ x,
                                                  unsigned short* __restrict__ lo,
                                                  unsigned short* __restrict__ hi) {
    int b = blockIdx.x / HS, h = blockIdx.x % HS;
    int strip = threadIdx.x >> 6, c = threadIdx.x & 63;
    int base = (b * HS + h) * WS * CH + c;
    const float* row = x + base;
    unsigned short* lop = lo + base;
    unsigned short* hip = hi + base;
    int w0s = strip * 14;
    float W[19];
#pragma unroll
    for (int t = 0; t < 19; ++t) W[t] = row[symi(w0s - 9 + t) * CH];
#pragma unroll
    for (int k = 0; k < 14; ++k) {
        int w = w0s + k;
        float aLo = 0.f, aHi = 0.f;
#pragma unroll
        for (int t = 0; t < 13; ++t) aLo += F_H0[t] * W[3 + t];
#pragma unroll
        for (int t = 0; t < 19; ++t) aHi += F_H1[t] * W[t];
        lop[w * CH] = f2bf(aLo);
        hip[w * CH] = f2bf(aHi);
#pragma unroll
        for (int t = 0; t < 18; ++t) W[t] = W[t + 1];
        W[18] = row[symi(w + 10) * CH];
    }
}

// ---- K2a: lo column filters -> xl (fp32) + subband planes 0,1,10,11 (bf16)
__global__ __launch_bounds__(256) void k_cols_lo(
    const unsigned short* __restrict__ lo, const float* __restrict__ wllT,
    float* __restrict__ xl, unsigned short* __restrict__ sbT) {
    __shared__ float qT[4][64][29];  // 29.7 KB, pad 29 conflict-free
    int b = blockIdx.x / WH, wp = blockIdx.x % WH;
    int w0 = 2 * wp, tid = threadIdx.x;
    int q = tid >> 6, c = tid & 63;
    int rp = q >> 1, jc = q & 1;
    const unsigned short* colbase = lo + (b * HS) * WS * CH + (w0 + jc) * CH + c;
    {
        float W[19];
#pragma unroll
        for (int t = 0; t < 19; ++t) W[t] = bf2f(colbase[symi(rp - 9 + t) * (WS * CH)]);
#pragma unroll
        for (int i = 0; i < 28; ++i) {
            int h = 2 * i + rp;
            float vll = 0.f, vlh = 0.f;
#pragma unroll
            for (int t = 0; t < 13; ++t) vll += F_H0[t] * W[3 + t];
#pragma unroll
            for (int t = 0; t < 19; ++t) vlh += F_H1[t] * W[t];
            xl[((b * HS + h) * WS + (w0 + jc)) * CH + c] =
                vll * wllT[(h * WS + (w0 + jc)) * CH + c];
            qT[q][c][i] = vlh;
#pragma unroll
            for (int t = 0; t < 17; ++t) W[t] = W[t + 2];
            W[17] = bf2f(colbase[symi(h + 10) * (WS * CH)]);
            W[18] = bf2f(colbase[symi(h + 11) * (WS * CH)]);
        }
    }
    __syncthreads();
    // fused q2c + bf16 pack + transposed store
    // j=q: 0:(a-d)->p0  1:(b+c)->p1  2:(a+d)->p10  3:(b-c)->p11
    int rowA = q & 1, rowB = 3 - (q & 1);
    float sgn = (q == 1 || q == 2) ? 1.f : -1.f;
    int p = (q < 2) ? q : q + 8;
    const float* qA = &qT[rowA][c][0];
    const float* qB = &qT[rowB][c][0];
    unsigned short* dst = sbT + ((p * 64 + c) * BT + b) * PPOS + wp * 28;
#pragma unroll
    for (int g = 0; g < 7; ++g) {
        float4 a4 = *(const float4*)(qA + g * 4);
        float4 b4 = *(const float4*)(qB + g * 4);
        float v0 = (a4.x + sgn * b4.x) * ISQ2;
        float v1 = (a4.y + sgn * b4.y) * ISQ2;
        float v2 = (a4.z + sgn * b4.z) * ISQ2;
        float v3 = (a4.w + sgn * b4.w) * ISQ2;
        uint2 pk;
        pk.x = (unsigned)f2bf(v0) | ((unsigned)f2bf(v1) << 16);
        pk.y = (unsigned)f2bf(v2) | ((unsigned)f2bf(v3) << 16);
        *(uint2*)(dst + g * 4) = pk;
    }
}

// ---- K2b: hi column filters, split by filter via blockIdx.y:
//   y=0: H0col (hl) -> planes 4,5,6,7 (s2,s3); y=1: H1col (hh) -> 2,3,8,9 (s1,s4)
__global__ __launch_bounds__(256) void k_cols_hi(const unsigned short* __restrict__ hi,
                                                 unsigned short* __restrict__ sbT) {
    __shared__ float qT[4][64][29];  // 29.7 KB -> 5 blocks/CU
    int srcy = blockIdx.y;
    int b = blockIdx.x / WH, wp = blockIdx.x % WH;
    int w0 = 2 * wp, tid = threadIdx.x;
    int q = tid >> 6, c = tid & 63;
    int rp = q >> 1, jc = q & 1;
    const unsigned short* colbase = hi + (b * HS) * WS * CH + (w0 + jc) * CH + c;
    if (srcy == 0) {  // 13-tap H0 column filter
        float W[13];
#pragma unroll
        for (int t = 0; t < 13; ++t) W[t] = bf2f(colbase[symi(rp - 6 + t) * (WS * CH)]);
#pragma unroll
        for (int i = 0; i < 28; ++i) {
            int h = 2 * i + rp;
            float v = 0.f;
#pragma unroll
            for (int t = 0; t < 13; ++t) v += F_H0[t] * W[t];
            qT[q][c][i] = v;
#pragma unroll
            for (int t = 0; t < 11; ++t) W[t] = W[t + 2];
            W[11] = bf2f(colbase[symi(h + 7) * (WS * CH)]);
            W[12] = bf2f(colbase[symi(h + 8) * (WS * CH)]);
        }
    } else {  // 19-tap H1 column filter
        float W[19];
#pragma unroll
        for (int t = 0; t < 19; ++t) W[t] = bf2f(colbase[symi(rp - 9 + t) * (WS * CH)]);
#pragma unroll
        for (int i = 0; i < 28; ++i) {
            int h = 2 * i + rp;
            float v = 0.f;
#pragma unroll
            for (int t = 0; t < 19; ++t) v += F_H1[t] * W[t];
            qT[q][c][i] = v;
#pragma unroll
            for (int t = 0; t < 17; ++t) W[t] = W[t + 2];
            W[17] = bf2f(colbase[symi(h + 10) * (WS * CH)]);
            W[18] = bf2f(colbase[symi(h + 11) * (WS * CH)]);
        }
    }
    __syncthreads();
    int rowA = q & 1, rowB = 3 - (q & 1);
    float sgn = (q == 1 || q == 2) ? 1.f : -1.f;
    int p = (srcy == 0) ? (4 + q) : ((q < 2) ? (2 + q) : (6 + q));
    const float* qA = &qT[rowA][c][0];
    const float* qB = &qT[rowB][c][0];
    unsigned short* dst = sbT + ((p * 64 + c) * BT + b) * PPOS + wp * 28;
#pragma unroll
    for (int g = 0; g < 7; ++g) {
        float4 a4 = *(const float4*)(qA + g * 4);
        float4 b4 = *(const float4*)(qB + g * 4);
        float v0 = (a4.x + sgn * b4.x) * ISQ2;
        float v1 = (a4.y + sgn * b4.y) * ISQ2;
        float v2 = (a4.z + sgn * b4.z) * ISQ2;
        float v3 = (a4.w + sgn * b4.w) * ISQ2;
        uint2 pk;
        pk.x = (unsigned)f2bf(v0) | ((unsigned)f2bf(v1) << 16);
        pk.y = (unsigned)f2bf(v2) | ((unsigned)f2bf(v3) << 16);
        *(uint2*)(dst + g * 4) = pk;
    }
}

// ---- K3: MFMA channel mixing + fused c2q -> bf16 planes P[b][h][w][c]
//   pr 0: (s0,s5)->P0 ; pr 1: (s2,s3)->P1 ; pr 2: (s1,s4)->P2
__global__ __launch_bounds__(256) void k_mix(
    const unsigned short* __restrict__ sbT, const float* __restrict__ w1,
    const float* __restrict__ w2, const float* __restrict__ b1,
    const float* __restrict__ b2, unsigned short* __restrict__ P0,
    unsigned short* __restrict__ P1, unsigned short* __restrict__ P2) {
    __shared__ unsigned short l1a[4][16][36];
    __shared__ unsigned short l1b[4][16][36];
    int blk = blockIdx.x;
    int pr = blk / (BT * 7);
    int rem = blk % (BT * 7);
    int b = rem / 7;
    int chunk = rem % 7;
    int sa = (pr == 0) ? 0 : (pr == 1) ? 2 : 1;
    int sb = (pr == 0) ? 5 : (pr == 1) ? 3 : 4;
    unsigned short* Pd = (pr == 0) ? P0 : (pr == 1) ? P1 : P2;
    int tid = threadIdx.x;
    int lane = tid & 63;
    int wv = tid >> 6;
    int nb = __builtin_amdgcn_readfirstlane(wv);
    int quad = lane >> 4;
    int n = lane & 15;

    short8 B1r, B1i, B2r, B2i;
#pragma unroll
    for (int j = 0; j < 8; ++j) {
        int kk = quad * 8 + j;
        int riw = kk >> 4, dd = kk & 15;
        float v1r = w1[nb * 256 + dd * 16 + n];
        float v1i = w1[1024 + nb * 256 + dd * 16 + n];
        float v2r = w2[nb * 256 + dd * 16 + n];
        float v2i = w2[1024 + nb * 256 + dd * 16 + n];
        B1r[j] = (short)f2bf(riw ? -v1i : v1r);
        B1i[j] = (short)f2bf(riw ? v1r : v1i);
        B2r[j] = (short)f2bf(riw ? -v2i : v2r);
        B2i[j] = (short)f2bf(riw ? v2r : v2i);
    }
    float bias1r = b1[nb * 16 + n], bias1i = b1[64 + nb * 16 + n];
    float bias2r = b2[nb * 16 + n], bias2i = b2[64 + nb * 16 + n];

    int pbase = chunk * 112;
    for (int t = 0; t < 7; ++t) {
        int pos0 = pbase + t * 16;
        short8 A1a, A1b;
#pragma unroll
        for (int j = 0; j < 8; ++j) {
            int kk = quad * 8 + j;
            int rix = kk >> 4, dd = kk & 15;
            int cc = nb * 16 + dd;
            A1a[j] = (short)sbT[(((sa * 2 + rix) * 64 + cc) * BT + b) * PPOS + pos0 + n];
            A1b[j] = (short)sbT[(((sb * 2 + rix) * 64 + cc) * BT + b) * PPOS + pos0 + n];
        }
        f32x4 a1r = {bias1r, bias1r, bias1r, bias1r};
        f32x4 a1i = {bias1i, bias1i, bias1i, bias1i};
        f32x4 b1r_ = a1r, b1i_ = a1i;
        a1r = __builtin_amdgcn_mfma_f32_16x16x32_bf16(A1a, B1r, a1r, 0, 0, 0);
        a1i = __builtin_amdgcn_mfma_f32_16x16x32_bf16(A1a, B1i, a1i, 0, 0, 0);
        b1r_ = __builtin_amdgcn_mfma_f32_16x16x32_bf16(A1b, B1r, b1r_, 0, 0, 0);
        b1i_ = __builtin_amdgcn_mfma_f32_16x16x32_bf16(A1b, B1i, b1i_, 0, 0, 0);
#pragma unroll
        for (int r = 0; r < 4; ++r) {
            int pos = quad * 4 + r;
            l1a[wv][pos][n] = f2bf(fmaxf(a1r[r], 0.f));
            l1a[wv][pos][16 + n] = f2bf(fmaxf(a1i[r], 0.f));
            l1b[wv][pos][n] = f2bf(fmaxf(b1r_[r], 0.f));
            l1b[wv][pos][16 + n] = f2bf(fmaxf(b1i_[r], 0.f));
        }
        union { short8 s8; uint2 u2[2]; } a2a, a2b;
        const unsigned short* rowpa = &l1a[wv][n][0];
        const unsigned short* rowpb = &l1b[wv][n][0];
        a2a.u2[0] = *(const uint2*)(rowpa + quad * 8);
        a2a.u2[1] = *(const uint2*)(rowpa + quad * 8 + 4);
        a2b.u2[0] = *(const uint2*)(rowpb + quad * 8);
        a2b.u2[1] = *(const uint2*)(rowpb + quad * 8 + 4);
        f32x4 aAr = {bias2r, bias2r, bias2r, bias2r};
        f32x4 aAi = {bias2i, bias2i, bias2i, bias2i};
        f32x4 aBr = aAr, aBi = aAi;
        aAr = __builtin_amdgcn_mfma_f32_16x16x32_bf16(a2a.s8, B2r, aAr, 0, 0, 0);
        aAi = __builtin_amdgcn_mfma_f32_16x16x32_bf16(a2a.s8, B2i, aAi, 0, 0, 0);
        aBr = __builtin_amdgcn_mfma_f32_16x16x32_bf16(a2b.s8, B2r, aBr, 0, 0, 0);
        aBi = __builtin_amdgcn_mfma_f32_16x16x32_bf16(a2b.s8, B2i, aBi, 0, 0, 0);
#pragma unroll
        for (int r = 0; r < 4; ++r) {
            int pos_g = pos0 + quad * 4 + r;
            int wp = pos_g / 28, ii = pos_g - wp * 28;
            int o = ((b * HS + 2 * ii) * WS + 2 * wp) * CH + nb * 16 + n;
            Pd[o] = f2bf((aAr[r] + aBr[r]) * ISQ2);
            Pd[o + CH] = f2bf((aAi[r] + aBi[r]) * ISQ2);
            Pd[o + WS * CH] = f2bf((aAi[r] - aBi[r]) * ISQ2);
            Pd[o + WS * CH + CH] = f2bf((aBr[r] - aAr[r]) * ISQ2);
        }
    }
}

// ---- K4: inverse column pass: out = G0col(A) + G1col(B)
// amode 0: A from fp32 plane (xl); amode 1: A from bf16 plane.
__global__ __launch_bounds__(256) void k_inv_cols2(
    const float* __restrict__ Af32, const unsigned short* __restrict__ Abf,
    const unsigned short* __restrict__ Bp, float* __restrict__ outp, int amode) {
    int b = blockIdx.x / 14, wg = blockIdx.x % 14;
    int wl = threadIdx.x >> 6, c = threadIdx.x & 63;
    int w = wg * 4 + wl;
    int base = (b * HS) * WS * CH + w * CH + c;
    const int st = WS * CH;
    auto ldA = [&](int r) -> float {
        return amode ? bf2f(Abf[base + r * st]) : Af32[base + r * st];
    };
    float A[19], B[13];
#pragma unroll
    for (int t = 0; t < 19; ++t) A[t] = ldA(symi(t - 9));
#pragma unroll
    for (int t = 0; t < 13; ++t) B[t] = bf2f(Bp[base + symi(t - 6) * st]);
#pragma unroll
    for (int h = 0; h < 56; ++h) {
        float acc = 0.f;
#pragma unroll
        for (int t = 0; t < 19; ++t) acc += F_G0[t] * A[t];
#pragma unroll
        for (int t = 0; t < 13; ++t) acc += F_G1[t] * B[t];
        outp[base + h * st] = acc;
#pragma unroll
        for (int t = 0; t < 18; ++t) A[t] = A[t + 1];
#pragma unroll
        for (int t = 0; t < 12; ++t) B[t] = B[t + 1];
        A[18] = ldA(symi(h + 10));
        B[12] = bf2f(Bp[base + symi(h + 7) * st]);
    }
}

// ---- K5: inverse row filters (sliding window, no LDS) -> out (fp32)
__global__ __launch_bounds__(256) void k_inv_rows(const float* __restrict__ lo2,
                                                  const float* __restrict__ hi2,
                                                  float* __restrict__ out) {
    int b = blockIdx.x / HS, h = blockIdx.x % HS;
    int strip = threadIdx.x >> 6, c = threadIdx.x & 63;
    int base = (b * HS + h) * WS * CH + c;
    const float* rlo = lo2 + base;
    const float* rhi = hi2 + base;
    float* op = out + base;
    int w0s = strip * 14;
    float A[19], B[13];
#pragma unroll
    for (int t = 0; t < 19; ++t) A[t] = rlo[symi(w0s - 9 + t) * CH];
#pragma unroll
    for (int t = 0; t < 13; ++t) B[t] = rhi[symi(w0s - 6 + t) * CH];
#pragma unroll
    for (int k = 0; k < 14; ++k) {
        int w = w0s + k;
        float acc = 0.f;
#pragma unroll
        for (int t = 0; t < 19; ++t) acc += F_G0[t] * A[t];
#pragma unroll
        for (int t = 0; t < 13; ++t) acc += F_G1[t] * B[t];
        op[w * CH] = acc;
#pragma unroll
        for (int t = 0; t < 18; ++t) A[t] = A[t + 1];
#pragma unroll
        for (int t = 0; t < 12; ++t) B[t] = B[t + 1];
        A[18] = rlo[symi(w + 10) * CH];
        B[12] = rhi[symi(w + 7) * CH];
    }
}

extern "C" void kernel_launch(void* const* d_in, const int* in_sizes, int n_in,
                              void* d_out, int out_size, void* d_ws, size_t ws_size,
                              hipStream_t stream) {
    const float* x = (const float*)d_in[0];
    const float* w_ll = (const float*)d_in[1];
    const float* w1 = (const float*)d_in[2];
    const float* w2 = (const float*)d_in[3];
    const float* b1 = (const float*)d_in[4];
    const float* b2 = (const float*)d_in[5];
    float* out = (float*)d_out;

    // workspace map (float units). A = 6,422,528 elems; SBf = sbT in fl = 9,633,792.
    // total = A + SBf + 5*(A/2) = 32.1M fl = 128.5 MB (< R1-proven 154 MB)
    const size_t A = (size_t)BT * HS * WS * CH;
    const size_t SBf = (size_t)12 * 64 * BT * PPOS / 2;
    float* wsf = (float*)d_ws;
    float* xl = wsf;                                    // [0,A) fp32, dead after inv a
    float* hi2 = wsf;                                   //   .. then hi2 (fp32, inv b)
    unsigned short* sbT = (unsigned short*)(wsf + A);   // [A,A+SBf) dead after mix
    float* lo2 = wsf + A;                               //   .. then lo2 (fp32, A<=SBf)
    unsigned short* lo_in = (unsigned short*)(wsf + A + SBf);   // bf16, A/2 fl
    unsigned short* hi_in = lo_in + A;                  // bf16
    unsigned short* P0 = hi_in + A;                     // bf16
    unsigned short* P1 = P0 + A;
    unsigned short* P2 = P1 + A;

    float* wllT = out;  // staged in d_out head (overwritten by k_inv_rows)

    k_wll_T<<<49, 256, 0, stream>>>(w_ll, wllT);
    k_fwd_rows<<<BT * HS, 256, 0, stream>>>(x, lo_in, hi_in);
    k_cols_lo<<<BT * WH, 256, 0, stream>>>(lo_in, wllT, xl, sbT);
    k_cols_hi<<<dim3(BT * WH, 2), 256, 0, stream>>>(hi_in, sbT);
    k_mix<<<3 * BT * 7, 256, 0, stream>>>(sbT, w1, w2, b1, b2, P0, P1, P2);
    k_inv_cols2<<<BT * 14, 256, 0, stream>>>(xl, (unsigned short*)nullptr, P0, lo2, 0);
    k_inv_cols2<<<BT * 14, 256, 0, stream>>>(nullptr, P1, P2, hi2, 1);
    k_inv_rows<<<BT * HS, 256, 0, stream>>>(lo2, hi2, out);
}

// Round 10
// 219.147 us; speedup vs baseline: 1.0855x; 1.0855x over previous
//
#include <hip/hip_runtime.h>

#define BT 32
#define CH 64
#define HS 56
#define WS 56
#define HH 28
#define WH 28

// ---------------- filter constants (exact reference values) ----------------
namespace {
constexpr float ISQ2 = 0.70710678118654752440f;
constexpr float F_H0[13] = {-0.0017578125f, 0.0f, 0.022265625f, -0.046875f,
    -0.0482421875f, 0.296875f, 0.55546875f, 0.296875f, -0.0482421875f,
    -0.046875f, 0.022265625f, 0.0f, -0.0017578125f};
constexpr float F_H1[19] = {-7.0626e-05f, 0.0f, 0.00134189f, -0.00188341f,
    -0.0071566f, 0.023856f, 0.0556431f, -0.0516881f, -0.299758f, 0.559431f,
    -0.299758f, -0.0516881f, 0.0556431f, 0.023856f, -0.0071566f,
    -0.00188341f, 0.00134189f, 0.0f, -7.0626e-05f};
constexpr float F_G0[19] = {7.0626e-05f, 0.0f, -0.00134189f, -0.00188341f,
    0.0071566f, 0.023856f, -0.0556431f, -0.0516881f, 0.299758f, 0.559431f,
    0.299758f, -0.0516881f, -0.0556431f, 0.023856f, 0.0071566f,
    -0.00188341f, -0.00134189f, 0.0f, 7.0626e-05f};
constexpr float F_G1[13] = {-0.0017578125f, 0.0f, 0.022265625f, 0.046875f,
    -0.0482421875f, -0.296875f, 0.55546875f, -0.296875f, -0.0482421875f,
    0.046875f, 0.022265625f, 0.0f, -0.0017578125f};
}

__device__ __forceinline__ int symi(int k) {
    k = (k < 0) ? (-1 - k) : k;
    k = (k >= HS) ? (2 * HS - 1 - k) : k;
    return k;
}

__device__ __forceinline__ unsigned short f2bf(float f) {  // RNE bf16
    unsigned u = __float_as_uint(f);
    u += 0x7fffu + ((u >> 16) & 1u);
    return (unsigned short)(u >> 16);
}
__device__ __forceinline__ float bf2f(unsigned short h) {
    return __uint_as_float(((unsigned)h) << 16);
}

typedef __attribute__((ext_vector_type(8))) short short8;  // 8 bf16 (4 VGPR)
typedef __attribute__((ext_vector_type(4))) float f32x4;

// sbT layout: plane p = s*2 + ri (12 planes), [p][c 64][b 32][pos 784], bf16
#define PPOS 784
#define PS (BT * PPOS)

// ---- K0: transpose w_ll [c][h][w] -> wllT [h][w][c] (staged in d_out head)
__global__ __launch_bounds__(256) void k_wll_T(const float* __restrict__ wll,
                                               float* __restrict__ wllT) {
    __shared__ float tile[64][65];
    int pos0 = blockIdx.x * 64;
    int lp = threadIdx.x & 63, g = threadIdx.x >> 6;
#pragma unroll
    for (int r = 0; r < 16; ++r) {
        int cc = r * 4 + g;
        tile[cc][lp] = wll[cc * (HS * WS) + pos0 + lp];
    }
    __syncthreads();
#pragma unroll
    for (int r = 0; r < 16; ++r) {
        int pl = r * 4 + g;
        wllT[(pos0 + pl) * CH + lp] = tile[lp][pl];
    }
}

// ---- K1: forward row filters (sliding window, no LDS): x -> lo, hi (bf16)
__global__ __launch_bounds__(256) void k_fwd_rows(const float* __restrict__ x,
                                                  unsigned short* __restrict__ lo,
                                                  unsigned short* __restrict__ hi) {
    int b = blockIdx.x / HS, h = blockIdx.x % HS;
    int strip = threadIdx.x >> 6, c = threadIdx.x & 63;
    int base = (b * HS + h) * WS * CH + c;
    const float* row = x + base;
    unsigned short* lop = lo + base;
    unsigned short* hip = hi + base;
    int w0s = strip * 14;
    float W[19];
#pragma unroll
    for (int t = 0; t < 19; ++t) W[t] = row[symi(w0s - 9 + t) * CH];
#pragma unroll
    for (int k = 0; k < 14; ++k) {
        int w = w0s + k;
        float aLo = 0.f, aHi = 0.f;
#pragma unroll
        for (int t = 0; t < 13; ++t) aLo += F_H0[t] * W[3 + t];
#pragma unroll
        for (int t = 0; t < 19; ++t) aHi += F_H1[t] * W[t];
        lop[w * CH] = f2bf(aLo);
        hip[w * CH] = f2bf(aHi);
#pragma unroll
        for (int t = 0; t < 18; ++t) W[t] = W[t + 1];
        W[18] = row[symi(w + 10) * CH];
    }
}

// ---- K2a: lo column filters, H-half split (blockIdx.y) -> xl + planes 0,1,10,11
__global__ __launch_bounds__(256) void k_cols_lo(
    const unsigned short* __restrict__ lo, const float* __restrict__ wllT,
    float* __restrict__ xl, unsigned short* __restrict__ sbT) {
    __shared__ float qT[4][64][15];  // 15.4 KB, pad 15 (gcd(15,32)=1)
    int hf = blockIdx.y;
    int b = blockIdx.x / WH, wp = blockIdx.x % WH;
    int w0 = 2 * wp, tid = threadIdx.x;
    int q = tid >> 6, c = tid & 63;
    int rp = q >> 1, jc = q & 1;
    const unsigned short* colbase = lo + (b * HS) * WS * CH + (w0 + jc) * CH + c;
    {
        int hstart = 2 * (hf * 14) + rp;
        float W[19];
#pragma unroll
        for (int t = 0; t < 19; ++t) W[t] = bf2f(colbase[symi(hstart - 9 + t) * (WS * CH)]);
#pragma unroll
        for (int ii = 0; ii < 14; ++ii) {
            int h = hstart + 2 * ii;
            float vll = 0.f, vlh = 0.f;
#pragma unroll
            for (int t = 0; t < 13; ++t) vll += F_H0[t] * W[3 + t];
#pragma unroll
            for (int t = 0; t < 19; ++t) vlh += F_H1[t] * W[t];
            xl[((b * HS + h) * WS + (w0 + jc)) * CH + c] =
                vll * wllT[(h * WS + (w0 + jc)) * CH + c];
            qT[q][c][ii] = vlh;
#pragma unroll
            for (int t = 0; t < 17; ++t) W[t] = W[t + 2];
            W[17] = bf2f(colbase[symi(h + 10) * (WS * CH)]);
            W[18] = bf2f(colbase[symi(h + 11) * (WS * CH)]);
        }
    }
    __syncthreads();
    // fused q2c + bf16 pack: j=q: 0:(a-d)->p0 1:(b+c)->p1 2:(a+d)->p10 3:(b-c)->p11
    int rowA = q & 1, rowB = 3 - (q & 1);
    float sgn = (q == 1 || q == 2) ? 1.f : -1.f;
    int p = (q < 2) ? q : q + 8;
    const float* qA = &qT[rowA][c][0];
    const float* qB = &qT[rowB][c][0];
    unsigned short* dst = sbT + ((p * 64 + c) * BT + b) * PPOS + wp * 28 + hf * 14;
#pragma unroll
    for (int g = 0; g < 7; ++g) {
        float2 a2 = *(const float2*)(qA + g * 2);
        float2 b2 = *(const float2*)(qB + g * 2);
        float v0 = (a2.x + sgn * b2.x) * ISQ2;
        float v1 = (a2.y + sgn * b2.y) * ISQ2;
        *(unsigned*)(dst + g * 2) = (unsigned)f2bf(v0) | ((unsigned)f2bf(v1) << 16);
    }
}

// ---- K2b: hi column filters, dual-filter single-read, H-half split
__global__ __launch_bounds__(256) void k_cols_hi(const unsigned short* __restrict__ hi,
                                                 unsigned short* __restrict__ sbT) {
    __shared__ float qT[2][4][64][15];  // 30.7 KB -> 5 blocks/CU
    int hf = blockIdx.y;
    int b = blockIdx.x / WH, wp = blockIdx.x % WH;
    int w0 = 2 * wp, tid = threadIdx.x;
    int q = tid >> 6, c = tid & 63;
    int rp = q >> 1, jc = q & 1;
    const unsigned short* colbase = hi + (b * HS) * WS * CH + (w0 + jc) * CH + c;
    {
        int hstart = 2 * (hf * 14) + rp;
        float W[19];
#pragma unroll
        for (int t = 0; t < 19; ++t) W[t] = bf2f(colbase[symi(hstart - 9 + t) * (WS * CH)]);
#pragma unroll
        for (int ii = 0; ii < 14; ++ii) {
            int h = hstart + 2 * ii;
            float vhl = 0.f, vhh = 0.f;
#pragma unroll
            for (int t = 0; t < 13; ++t) vhl += F_H0[t] * W[3 + t];
#pragma unroll
            for (int t = 0; t < 19; ++t) vhh += F_H1[t] * W[t];
            qT[0][q][c][ii] = vhl;
            qT[1][q][c][ii] = vhh;
#pragma unroll
            for (int t = 0; t < 17; ++t) W[t] = W[t + 2];
            W[17] = bf2f(colbase[symi(h + 10) * (WS * CH)]);
            W[18] = bf2f(colbase[symi(h + 11) * (WS * CH)]);
        }
    }
    __syncthreads();
    int rowA = q & 1, rowB = 3 - (q & 1);
    float sgn = (q == 1 || q == 2) ? 1.f : -1.f;
#pragma unroll
    for (int src = 0; src < 2; ++src) {
        // src0 (hl): planes 4,5,6,7 (s2,s3); src1 (hh): planes 2,3,8,9 (s1,s4)
        int p = (src == 0) ? (4 + q) : ((q < 2) ? (2 + q) : (6 + q));
        const float* qA = &qT[src][rowA][c][0];
        const float* qB = &qT[src][rowB][c][0];
        unsigned short* dst = sbT + ((p * 64 + c) * BT + b) * PPOS + wp * 28 + hf * 14;
#pragma unroll
        for (int g = 0; g < 7; ++g) {
            float2 a2 = *(const float2*)(qA + g * 2);
            float2 b2 = *(const float2*)(qB + g * 2);
            float v0 = (a2.x + sgn * b2.x) * ISQ2;
            float v1 = (a2.y + sgn * b2.y) * ISQ2;
            *(unsigned*)(dst + g * 2) = (unsigned)f2bf(v0) | ((unsigned)f2bf(v1) << 16);
        }
    }
}

// ---- K3: MFMA channel mixing + fused c2q -> bf16 planes P[b][h][w][c]
__global__ __launch_bounds__(256) void k_mix(
    const unsigned short* __restrict__ sbT, const float* __restrict__ w1,
    const float* __restrict__ w2, const float* __restrict__ b1,
    const float* __restrict__ b2, unsigned short* __restrict__ P0,
    unsigned short* __restrict__ P1, unsigned short* __restrict__ P2) {
    __shared__ unsigned short l1a[4][16][36];
    __shared__ unsigned short l1b[4][16][36];
    int blk = blockIdx.x;
    int pr = blk / (BT * 7);
    int rem = blk % (BT * 7);
    int b = rem / 7;
    int chunk = rem % 7;
    int sa = (pr == 0) ? 0 : (pr == 1) ? 2 : 1;
    int sb = (pr == 0) ? 5 : (pr == 1) ? 3 : 4;
    unsigned short* Pd = (pr == 0) ? P0 : (pr == 1) ? P1 : P2;
    int tid = threadIdx.x;
    int lane = tid & 63;
    int wv = tid >> 6;
    int nb = __builtin_amdgcn_readfirstlane(wv);
    int quad = lane >> 4;
    int n = lane & 15;

    short8 B1r, B1i, B2r, B2i;
#pragma unroll
    for (int j = 0; j < 8; ++j) {
        int kk = quad * 8 + j;
        int riw = kk >> 4, dd = kk & 15;
        float v1r = w1[nb * 256 + dd * 16 + n];
        float v1i = w1[1024 + nb * 256 + dd * 16 + n];
        float v2r = w2[nb * 256 + dd * 16 + n];
        float v2i = w2[1024 + nb * 256 + dd * 16 + n];
        B1r[j] = (short)f2bf(riw ? -v1i : v1r);
        B1i[j] = (short)f2bf(riw ? v1r : v1i);
        B2r[j] = (short)f2bf(riw ? -v2i : v2r);
        B2i[j] = (short)f2bf(riw ? v2r : v2i);
    }
    float bias1r = b1[nb * 16 + n], bias1i = b1[64 + nb * 16 + n];
    float bias2r = b2[nb * 16 + n], bias2i = b2[64 + nb * 16 + n];

    int pbase = chunk * 112;
    for (int t = 0; t < 7; ++t) {
        int pos0 = pbase + t * 16;
        short8 A1a, A1b;
#pragma unroll
        for (int j = 0; j < 8; ++j) {
            int kk = quad * 8 + j;
            int rix = kk >> 4, dd = kk & 15;
            int cc = nb * 16 + dd;
            A1a[j] = (short)sbT[(((sa * 2 + rix) * 64 + cc) * BT + b) * PPOS + pos0 + n];
            A1b[j] = (short)sbT[(((sb * 2 + rix) * 64 + cc) * BT + b) * PPOS + pos0 + n];
        }
        f32x4 a1r = {bias1r, bias1r, bias1r, bias1r};
        f32x4 a1i = {bias1i, bias1i, bias1i, bias1i};
        f32x4 b1r_ = a1r, b1i_ = a1i;
        a1r = __builtin_amdgcn_mfma_f32_16x16x32_bf16(A1a, B1r, a1r, 0, 0, 0);
        a1i = __builtin_amdgcn_mfma_f32_16x16x32_bf16(A1a, B1i, a1i, 0, 0, 0);
        b1r_ = __builtin_amdgcn_mfma_f32_16x16x32_bf16(A1b, B1r, b1r_, 0, 0, 0);
        b1i_ = __builtin_amdgcn_mfma_f32_16x16x32_bf16(A1b, B1i, b1i_, 0, 0, 0);
#pragma unroll
        for (int r = 0; r < 4; ++r) {
            int pos = quad * 4 + r;
            l1a[wv][pos][n] = f2bf(fmaxf(a1r[r], 0.f));
            l1a[wv][pos][16 + n] = f2bf(fmaxf(a1i[r], 0.f));
            l1b[wv][pos][n] = f2bf(fmaxf(b1r_[r], 0.f));
            l1b[wv][pos][16 + n] = f2bf(fmaxf(b1i_[r], 0.f));
        }
        union { short8 s8; uint2 u2[2]; } a2a, a2b;
        const unsigned short* rowpa = &l1a[wv][n][0];
        const unsigned short* rowpb = &l1b[wv][n][0];
        a2a.u2[0] = *(const uint2*)(rowpa + quad * 8);
        a2a.u2[1] = *(const uint2*)(rowpa + quad * 8 + 4);
        a2b.u2[0] = *(const uint2*)(rowpb + quad * 8);
        a2b.u2[1] = *(const uint2*)(rowpb + quad * 8 + 4);
        f32x4 aAr = {bias2r, bias2r, bias2r, bias2r};
        f32x4 aAi = {bias2i, bias2i, bias2i, bias2i};
        f32x4 aBr = aAr, aBi = aAi;
        aAr = __builtin_amdgcn_mfma_f32_16x16x32_bf16(a2a.s8, B2r, aAr, 0, 0, 0);
        aAi = __builtin_amdgcn_mfma_f32_16x16x32_bf16(a2a.s8, B2i, aAi, 0, 0, 0);
        aBr = __builtin_amdgcn_mfma_f32_16x16x32_bf16(a2b.s8, B2r, aBr, 0, 0, 0);
        aBi = __builtin_amdgcn_mfma_f32_16x16x32_bf16(a2b.s8, B2i, aBi, 0, 0, 0);
#pragma unroll
        for (int r = 0; r < 4; ++r) {
            int pos_g = pos0 + quad * 4 + r;
            int wp = pos_g / 28, ii = pos_g - wp * 28;
            int o = ((b * HS + 2 * ii) * WS + 2 * wp) * CH + nb * 16 + n;
            Pd[o] = f2bf((aAr[r] + aBr[r]) * ISQ2);
            Pd[o + CH] = f2bf((aAi[r] + aBi[r]) * ISQ2);
            Pd[o + WS * CH] = f2bf((aAi[r] - aBi[r]) * ISQ2);
            Pd[o + WS * CH + CH] = f2bf((aBr[r] - aAr[r]) * ISQ2);
        }
    }
}

// ---- K4: inverse column pass, merged modes + H-half split:
//   z=0: lo2 = G0col(xl fp32) + G1col(P0);  z=1: hi2 = G0col(P1) + G1col(P2)
__global__ __launch_bounds__(256) void k_inv_cols(
    const float* __restrict__ xl, const unsigned short* __restrict__ P0,
    const unsigned short* __restrict__ P1, const unsigned short* __restrict__ P2,
    float* __restrict__ lo2, float* __restrict__ hi2) {
    int hf = blockIdx.y, mode = blockIdx.z;
    int b = blockIdx.x / 14, wg = blockIdx.x % 14;
    int wl = threadIdx.x >> 6, c = threadIdx.x & 63;
    int w = wg * 4 + wl;
    int base = (b * HS) * WS * CH + w * CH + c;
    const int st = WS * CH;
    const unsigned short* Abf = (mode == 0) ? P0 : P1;  // unused A slot in mode0
    const unsigned short* Bp = (mode == 0) ? P0 : P2;
    float* outp = (mode == 0) ? lo2 : hi2;
    auto ldA = [&](int r) -> float {
        return (mode == 0) ? xl[base + r * st] : bf2f(P1[base + r * st]);
    };
    (void)Abf;
    int h0 = hf * 28;
    float A[19], B[13];
#pragma unroll
    for (int t = 0; t < 19; ++t) A[t] = ldA(symi(h0 - 9 + t));
#pragma unroll
    for (int t = 0; t < 13; ++t) B[t] = bf2f(Bp[base + symi(h0 - 6 + t) * st]);
#pragma unroll
    for (int hh = 0; hh < 28; ++hh) {
        int h = h0 + hh;
        float acc = 0.f;
#pragma unroll
        for (int t = 0; t < 19; ++t) acc += F_G0[t] * A[t];
#pragma unroll
        for (int t = 0; t < 13; ++t) acc += F_G1[t] * B[t];
        outp[base + h * st] = acc;
#pragma unroll
        for (int t = 0; t < 18; ++t) A[t] = A[t + 1];
#pragma unroll
        for (int t = 0; t < 12; ++t) B[t] = B[t + 1];
        A[18] = ldA(symi(h + 10));
        B[12] = bf2f(Bp[base + symi(h + 7) * st]);
    }
}

// ---- K5: inverse row filters (sliding window, no LDS) -> out (fp32)
__global__ __launch_bounds__(256) void k_inv_rows(const float* __restrict__ lo2,
                                                  const float* __restrict__ hi2,
                                                  float* __restrict__ out) {
    int b = blockIdx.x / HS, h = blockIdx.x % HS;
    int strip = threadIdx.x >> 6, c = threadIdx.x & 63;
    int base = (b * HS + h) * WS * CH + c;
    const float* rlo = lo2 + base;
    const float* rhi = hi2 + base;
    float* op = out + base;
    int w0s = strip * 14;
    float A[19], B[13];
#pragma unroll
    for (int t = 0; t < 19; ++t) A[t] = rlo[symi(w0s - 9 + t) * CH];
#pragma unroll
    for (int t = 0; t < 13; ++t) B[t] = rhi[symi(w0s - 6 + t) * CH];
#pragma unroll
    for (int k = 0; k < 14; ++k) {
        int w = w0s + k;
        float acc = 0.f;
#pragma unroll
        for (int t = 0; t < 19; ++t) acc += F_G0[t] * A[t];
#pragma unroll
        for (int t = 0; t < 13; ++t) acc += F_G1[t] * B[t];
        op[w * CH] = acc;
#pragma unroll
        for (int t = 0; t < 18; ++t) A[t] = A[t + 1];
#pragma unroll
        for (int t = 0; t < 12; ++t) B[t] = B[t + 1];
        A[18] = rlo[symi(w + 10) * CH];
        B[12] = rhi[symi(w + 7) * CH];
    }
}

extern "C" void kernel_launch(void* const* d_in, const int* in_sizes, int n_in,
                              void* d_out, int out_size, void* d_ws, size_t ws_size,
                              hipStream_t stream) {
    const float* x = (const float*)d_in[0];
    const float* w_ll = (const float*)d_in[1];
    const float* w1 = (const float*)d_in[2];
    const float* w2 = (const float*)d_in[3];
    const float* b1 = (const float*)d_in[4];
    const float* b2 = (const float*)d_in[5];
    float* out = (float*)d_out;

    // workspace map (float units). A = 6,422,528; SBf = 9,633,792.
    // xl | sbT(->lo2) | hi2 | lo_in | hi_in | P0 | P1 | P2  = 38.5M fl = 154 MB
    const size_t A = (size_t)BT * HS * WS * CH;
    const size_t SBf = (size_t)12 * 64 * BT * PPOS / 2;
    float* wsf = (float*)d_ws;
    float* xl = wsf;                                    // fp32, read by inv mode0
    unsigned short* sbT = (unsigned short*)(wsf + A);   // dead after mix
    float* lo2 = wsf + A;                               //   .. reuses sbT region
    float* hi2 = wsf + A + SBf;                         // fp32 (no alias w/ xl!)
    unsigned short* lo_in = (unsigned short*)(wsf + A + SBf + A);
    unsigned short* hi_in = lo_in + A;                  // bf16
    unsigned short* P0 = hi_in + A;                     // bf16
    unsigned short* P1 = P0 + A;
    unsigned short* P2 = P1 + A;

    float* wllT = out;  // staged in d_out head (overwritten by k_inv_rows)

    k_wll_T<<<49, 256, 0, stream>>>(w_ll, wllT);
    k_fwd_rows<<<BT * HS, 256, 0, stream>>>(x, lo_in, hi_in);
    k_cols_lo<<<dim3(BT * WH, 2), 256, 0, stream>>>(lo_in, wllT, xl, sbT);
    k_cols_hi<<<dim3(BT * WH, 2), 256, 0, stream>>>(hi_in, sbT);
    k_mix<<<3 * BT * 7, 256, 0, stream>>>(sbT, w1, w2, b1, b2, P0, P1, P2);
    k_inv_cols<<<dim3(BT * 14, 2, 2), 256, 0, stream>>>(xl, P0, P1, P2, lo2, hi2);
    k_inv_rows<<<BT * HS, 256, 0, stream>>>(lo2, hi2, out);
}